// Round 2
// baseline (1118.264 us; speedup 1.0000x reference)
//
#include <hip/hip_runtime.h>
#include <hip/hip_bf16.h>

// GraphSAGE 3-layer: pool(64->64) -> pool(64->32) -> mean(32->32)
// Inputs: 0 x[N,64], 1 edge_index[2,E], 2 W1_pool, 3 b1_pool, 4 W1_self,
// 5 W1_neigh, 6 b1, 7 W2_pool, 8 b2_pool, 9 W2_self, 10 W2_neigh, 11 b2,
// 12 W3_self, 13 W3_neigh, 14 b3.
// Float inputs may be bf16 or f32 (runtime-detected). edge_index int32 or int64
// (runtime-detected). Output: f32 [N,32] (layer-3 f32 `cnt` forces f32 promotion).

typedef unsigned int uint;

__device__ __forceinline__ float bf2f(unsigned short h){
  return __uint_as_float(((unsigned int)h) << 16);
}
__device__ __forceinline__ unsigned short f2bf(float f){
  unsigned int u = __float_as_uint(f);
  u += 0x7fffu + ((u >> 16) & 1u);   // RNE
  return (unsigned short)(u >> 16);
}

// flags[0] = 1 if float inputs are bf16, 0 if f32.
// flags[1] = 1 if edge_index is int64, 0 if int32.
__global__ void detect_kernel(const void* x, const int* ei, int* flags){
  if (blockIdx.x == 0 && threadIdx.x == 0){
    // bf16 data: even-indexed ushorts are bf16 values of ~N(0,1) -> exponent
    // field in [118,134] nearly always. f32 data: even ushorts are low mantissa
    // bits -> exponent field ~uniform -> ~6% in range.
    const unsigned short* u = (const unsigned short*)x;
    int sane = 0;
    for (int i = 0; i < 512; i += 2){
      int e = (u[i] >> 7) & 0xff;
      if (e >= 118 && e <= 134) sane++;
    }
    flags[0] = (sane >= 128) ? 1 : 0;
    // int64 data: odd 32-bit words are high halves of values < 2^31 -> all 0.
    int z = 1;
    for (int i = 1; i < 128; i += 2) if (ei[i] != 0){ z = 0; break; }
    flags[1] = z;
  }
}

struct WConv {
  const void* src[13];
  float* dst[13];
  int n[13];
};

__global__ void conv_w(WConv wc, const int* flags){
  int t = blockIdx.x;
  int n = wc.n[t];
  float* d = wc.dst[t];
  if (flags[0]){
    const unsigned short* s = (const unsigned short*)wc.src[t];
    for (int i = threadIdx.x; i < n; i += blockDim.x) d[i] = bf2f(s[i]);
  } else {
    const float* s = (const float*)wc.src[t];
    for (int i = threadIdx.x; i < n; i += blockDim.x) d[i] = s[i];
  }
}

__device__ __forceinline__ void load_edge(const void* ei, int E, int is64, int e,
                                          int& s, int& d){
  if (is64){
    const long long* p = (const long long*)ei;
    s = (int)p[e]; d = (int)p[E + e];
  } else {
    const int* p = (const int*)ei;
    s = p[e]; d = p[E + e];
  }
}

// wave-per-edge, lane = feature (64 feats). m >= 0 (post-relu), agg zero-inited,
// so atomicMax on the uint bit pattern == segment_max with isolated->0 semantics.
__global__ __launch_bounds__(256) void scatter_max64(
    const void* __restrict__ ei, const int* __restrict__ flags,
    const unsigned short* __restrict__ m, unsigned int* __restrict__ agg,
    int E, int N)
{
  int is64 = flags[1];
  int f = threadIdx.x & 63;
  int e0 = (int)((blockIdx.x * 256u + threadIdx.x) >> 6);
  int stride = (int)((gridDim.x * 256u) >> 6);
  for (int e = e0; e < E; e += stride){
    int s, d; load_edge(ei, E, is64, e, s, d);
    if ((unsigned)s >= (unsigned)N || (unsigned)d >= (unsigned)N) continue;
    float v = bf2f(m[(size_t)s * 64 + f]);
    if (v > 0.f) atomicMax(agg + (size_t)d * 64 + f, __float_as_uint(v));
  }
}

// 32 lanes per edge: sum h[src] (f32 rows of 32) into ssum[dst], count edges.
__global__ __launch_bounds__(256) void scatter_sum32(
    const void* __restrict__ ei, const int* __restrict__ flags,
    const float* __restrict__ h, float* __restrict__ ssum,
    float* __restrict__ cnt, int E, int N)
{
  int is64 = flags[1];
  int f = threadIdx.x & 31;
  int e0 = (int)((blockIdx.x * 256u + threadIdx.x) >> 5);
  int stride = (int)((gridDim.x * 256u) >> 5);
  for (int e = e0; e < E; e += stride){
    int s, d; load_edge(ei, E, is64, e, s, d);
    if ((unsigned)s >= (unsigned)N || (unsigned)d >= (unsigned)N) continue;
    float v = h[(size_t)s * 32 + f];
    atomicAdd(ssum + (size_t)d * 32 + f, v);
    if (f == 0) atomicAdd(cnt + d, 1.f);
  }
}

// out[r] = act( A[r]@Wa + (B[r]*scale)@Wb + bias ). One row per thread.
// AMODE: 0 = A always bf16, 1 = A always f32, 2 = runtime (flags[0]).
template<int K, int C, bool RELU, bool HAS_B, bool MEAN, bool OUTF32, int AMODE>
__global__ __launch_bounds__(256) void dual_mm(
    const void* __restrict__ Av, const float* __restrict__ B,
    const float* __restrict__ Wa, const float* __restrict__ Wb,
    const float* __restrict__ bias, const float* __restrict__ cnt,
    const int* __restrict__ flags, void* __restrict__ outv, int n)
{
  int r = blockIdx.x * 256 + threadIdx.x;
  if (r >= n) return;

  bool af32 = (AMODE == 1) || (AMODE == 2 && flags[0] == 0);
  float a[K];
  if (af32){
    const float4* ap = (const float4*)((const float*)Av + (size_t)r * K);
    #pragma unroll
    for (int k4 = 0; k4 < K / 4; ++k4){
      float4 v = ap[k4];
      a[4*k4+0] = v.x; a[4*k4+1] = v.y; a[4*k4+2] = v.z; a[4*k4+3] = v.w;
    }
  } else {
    const uint4* ap = (const uint4*)((const unsigned short*)Av + (size_t)r * K);
    #pragma unroll
    for (int k8 = 0; k8 < K / 8; ++k8){
      uint4 pk = ap[k8];
      uint w0 = pk.x, w1 = pk.y, w2 = pk.z, w3 = pk.w;
      a[k8*8+0] = __uint_as_float(w0 << 16); a[k8*8+1] = __uint_as_float(w0 & 0xffff0000u);
      a[k8*8+2] = __uint_as_float(w1 << 16); a[k8*8+3] = __uint_as_float(w1 & 0xffff0000u);
      a[k8*8+4] = __uint_as_float(w2 << 16); a[k8*8+5] = __uint_as_float(w2 & 0xffff0000u);
      a[k8*8+6] = __uint_as_float(w3 << 16); a[k8*8+7] = __uint_as_float(w3 & 0xffff0000u);
    }
  }
  float b[HAS_B ? K : 1];
  if constexpr (HAS_B){
    float scale = 1.f;
    if constexpr (MEAN){ scale = 1.f / fmaxf(cnt[r], 1.f); }
    const float4* bp = (const float4*)(B + (size_t)r * K);
    #pragma unroll
    for (int k4 = 0; k4 < K / 4; ++k4){
      float4 v = bp[k4];
      b[4*k4+0] = v.x * scale; b[4*k4+1] = v.y * scale;
      b[4*k4+2] = v.z * scale; b[4*k4+3] = v.w * scale;
    }
  }
  #pragma unroll
  for (int c0 = 0; c0 < C; c0 += 8){
    float acc[8];
    #pragma unroll
    for (int j = 0; j < 8; ++j) acc[j] = bias[c0 + j];
    #pragma unroll
    for (int k = 0; k < K; ++k){
      float av = a[k];
      #pragma unroll
      for (int j = 0; j < 8; ++j) acc[j] = fmaf(av, Wa[k * C + c0 + j], acc[j]);
    }
    if constexpr (HAS_B){
      #pragma unroll
      for (int k = 0; k < K; ++k){
        float bv = b[k];
        #pragma unroll
        for (int j = 0; j < 8; ++j) acc[j] = fmaf(bv, Wb[k * C + c0 + j], acc[j]);
      }
    }
    #pragma unroll
    for (int j = 0; j < 8; ++j){ if constexpr (RELU) acc[j] = fmaxf(acc[j], 0.f); }

    if constexpr (OUTF32){
      float* orow = (float*)outv + (size_t)r * C + c0;
      float4 v0 = {acc[0], acc[1], acc[2], acc[3]};
      float4 v1 = {acc[4], acc[5], acc[6], acc[7]};
      *(float4*)(orow) = v0;
      *(float4*)(orow + 4) = v1;
    } else {
      unsigned short* orow = (unsigned short*)outv + (size_t)r * C + c0;
      uint4 pk;
      pk.x = (uint)f2bf(acc[0]) | ((uint)f2bf(acc[1]) << 16);
      pk.y = (uint)f2bf(acc[2]) | ((uint)f2bf(acc[3]) << 16);
      pk.z = (uint)f2bf(acc[4]) | ((uint)f2bf(acc[5]) << 16);
      pk.w = (uint)f2bf(acc[6]) | ((uint)f2bf(acc[7]) << 16);
      *(uint4*)(orow) = pk;
    }
  }
}

extern "C" void kernel_launch(void* const* d_in, const int* in_sizes, int n_in,
                              void* d_out, int out_size, void* d_ws, size_t ws_size,
                              hipStream_t stream)
{
  const void* x = d_in[0];
  const void* ei = d_in[1];
  int N = in_sizes[0] / 64;   // 100000
  int E = in_sizes[1] / 2;    // 1600000

  char* ws = (char*)d_ws;
  // Weights as f32 at ws head (22784 floats; reserve 128KB incl. flags).
  float* wf = (float*)ws;
  float* W1p = wf + 0;     float* b1p = wf + 4096;
  float* W1s = wf + 4160;  float* W1n = wf + 8256;  float* b1 = wf + 12352;
  float* W2p = wf + 12416; float* b2p = wf + 16512;
  float* W2s = wf + 16576; float* W2n = wf + 18624; float* b2 = wf + 20672;
  float* W3s = wf + 20704; float* W3n = wf + 21728; float* b3 = wf + 22752;
  int* flags = (int*)(ws + 131072 - 256);

  // Big buffers: 131072 + 12.8M + 25.6M + 12.8M + 0.4M = 51.7MB total.
  char* p = ws + 131072;
  unsigned short* mbuf = (unsigned short*)p; p += (size_t)N * 64 * 2;  // m1/m2 bf16
  float* agg = (float*)p;                    p += (size_t)N * 64 * 4;  // agg1/agg2/s3
  unsigned short* h1 = (unsigned short*)p;   p += (size_t)N * 64 * 2;  // h1 bf16
  float* cnt = (float*)p;                    p += (size_t)N * 4;
  float* h2 = (float*)d_out;  // N*32 f32 == d_out exactly; dead until final kernel

  hipLaunchKernelGGL(detect_kernel, dim3(1), dim3(64), 0, stream,
                     x, (const int*)ei, flags);

  WConv wc;
  {
    const int widx[13] = {2,3,4,5,6,7,8,9,10,11,12,13,14};
    float* wdst[13] = {W1p,b1p,W1s,W1n,b1,W2p,b2p,W2s,W2n,b2,W3s,W3n,b3};
    for (int i = 0; i < 13; ++i){
      wc.src[i] = d_in[widx[i]];
      wc.dst[i] = wdst[i];
      wc.n[i] = in_sizes[widx[i]];
    }
  }
  hipLaunchKernelGGL(conv_w, dim3(13), dim3(256), 0, stream, wc, flags);

  int gmm = (N + 255) / 256;

  // ---- layer 1 (pool 64->64, relu) ----
  hipMemsetAsync(agg, 0, (size_t)N * 64 * 4, stream);
  dual_mm<64,64,true,false,false,false,2><<<gmm,256,0,stream>>>(
      x, nullptr, W1p, nullptr, b1p, nullptr, flags, mbuf, N);
  scatter_max64<<<8192,256,0,stream>>>(ei, flags, mbuf, (unsigned int*)agg, E, N);
  dual_mm<64,64,true,true,false,false,2><<<gmm,256,0,stream>>>(
      x, agg, W1s, W1n, b1, nullptr, flags, h1, N);

  // ---- layer 2 (pool 64->32, no act); h2 lives in d_out ----
  hipMemsetAsync(agg, 0, (size_t)N * 64 * 4, stream);
  dual_mm<64,64,true,false,false,false,0><<<gmm,256,0,stream>>>(
      h1, nullptr, W2p, nullptr, b2p, nullptr, flags, mbuf, N);
  scatter_max64<<<8192,256,0,stream>>>(ei, flags, mbuf, (unsigned int*)agg, E, N);
  dual_mm<64,32,false,true,false,true,0><<<gmm,256,0,stream>>>(
      h1, agg, W2s, W2n, b2, nullptr, flags, h2, N);

  // ---- layer 3 (mean 32->32, f32 out, in-place on d_out) ----
  hipMemsetAsync(agg, 0, (size_t)N * 32 * 4, stream);
  hipMemsetAsync(cnt, 0, (size_t)N * 4, stream);
  scatter_sum32<<<8192,256,0,stream>>>(ei, flags, h2, agg, cnt, E, N);
  dual_mm<32,32,false,true,true,true,1><<<gmm,256,0,stream>>>(
      h2, agg, W3s, W3n, b3, cnt, flags, d_out, N);
}

// Round 3
// 851.937 us; speedup vs baseline: 1.3126x; 1.3126x over previous
//
#include <hip/hip_runtime.h>
#include <hip/hip_bf16.h>

// GraphSAGE 3-layer: pool(64->64) -> pool(64->32) -> mean(32->32)
// R3: CSR gather-reduce replaces atomic scatter (R2: 399MB atomic write-through
// per pool layer, 272us/dispatch). Only atomics left: histogram + bucket fill
// on a 400KB L2-resident array.

typedef unsigned int uint;

__device__ __forceinline__ float bf2f(unsigned short h){
  return __uint_as_float(((uint)h) << 16);
}
__device__ __forceinline__ unsigned short f2bf(float f){
  uint u = __float_as_uint(f);
  u += 0x7fffu + ((u >> 16) & 1u);   // RNE
  return (unsigned short)(u >> 16);
}

// flags[0]=1 if float inputs bf16 else f32; flags[1]=1 if edge_index int64.
__global__ void detect_kernel(const unsigned short* x, const int* ei, int* flags){
  int lane = threadIdx.x;  // 64 threads
  int sane = 0;
  #pragma unroll
  for (int k = 0; k < 4; ++k){
    int e = (x[(lane * 4 + k) * 2] >> 7) & 0xff;  // even ushort = bf16 value iff bf16
    sane += (e >= 118 && e <= 134);
  }
  #pragma unroll
  for (int off = 32; off; off >>= 1) sane += __shfl_down(sane, off, 64);
  unsigned long long b = __ballot(ei[1 + 2 * lane] != 0);  // odd words 0 iff int64
  if (lane == 0){ flags[0] = (sane >= 128); flags[1] = (b == 0ull); }
}

struct WConv { const void* src[13]; float* dst[13]; int n[13]; };

__global__ void conv_w(WConv wc, const int* flags){
  int t = blockIdx.x, n = wc.n[t];
  float* d = wc.dst[t];
  if (flags[0]){
    const unsigned short* s = (const unsigned short*)wc.src[t];
    for (int i = threadIdx.x; i < n; i += blockDim.x) d[i] = bf2f(s[i]);
  } else {
    const float* s = (const float*)wc.src[t];
    for (int i = threadIdx.x; i < n; i += blockDim.x) d[i] = s[i];
  }
}

__device__ __forceinline__ void load_edge(const void* ei, int E, int is64, int e,
                                          int& s, int& d){
  if (is64){
    const long long* p = (const long long*)ei;
    s = (int)p[e]; d = (int)p[E + e];
  } else {
    const int* p = (const int*)ei;
    s = p[e]; d = p[E + e];
  }
}

// ---------------- CSR build ----------------
__global__ __launch_bounds__(256) void edge_hist(
    const void* __restrict__ ei, const int* __restrict__ flags,
    int* __restrict__ deg, int E, int N)
{
  int is64 = flags[1];
  int i = blockIdx.x * 256 + threadIdx.x, stride = gridDim.x * 256;
  for (int e = i; e < E; e += stride){
    int s, d; load_edge(ei, E, is64, e, s, d);
    if ((unsigned)s >= (unsigned)N || (unsigned)d >= (unsigned)N) continue;
    atomicAdd(deg + d, 1);
  }
}

__global__ __launch_bounds__(256) void scan_blocksums(
    const int* __restrict__ deg, int* __restrict__ bsum, int N)
{
  __shared__ int sm[256];
  int b = blockIdx.x, t = threadIdx.x;
  int base = b * 1024 + t * 4, s = 0;
  #pragma unroll
  for (int k = 0; k < 4; ++k) if (base + k < N) s += deg[base + k];
  sm[t] = s; __syncthreads();
  for (int off = 128; off; off >>= 1){
    if (t < off) sm[t] += sm[t + off];
    __syncthreads();
  }
  if (t == 0) bsum[b] = sm[0];
}

__global__ void scan_bsum(int* bsum, int nb, int* rowptrN){
  __shared__ int sm[1024];
  int t = threadIdx.x;
  for (int i = t; i < nb; i += 256) sm[i] = bsum[i];
  __syncthreads();
  if (t == 0){
    int run = 0;
    for (int i = 0; i < nb; ++i){ int v = sm[i]; sm[i] = run; run += v; }
    *rowptrN = run;
  }
  __syncthreads();
  for (int i = t; i < nb; i += 256) bsum[i] = sm[i];
}

__global__ __launch_bounds__(256) void scan_final(
    const int* __restrict__ deg, const int* __restrict__ bsum,
    int* __restrict__ row_ptr, int* __restrict__ cursor, int N)
{
  __shared__ int sm[256];
  int b = blockIdx.x, t = threadIdx.x;
  int base = b * 1024 + t * 4;
  int v[4], s = 0;
  #pragma unroll
  for (int k = 0; k < 4; ++k){ v[k] = (base + k < N) ? deg[base + k] : 0; s += v[k]; }
  sm[t] = s; __syncthreads();
  for (int off = 1; off < 256; off <<= 1){
    int x = (t >= off) ? sm[t - off] : 0;
    __syncthreads();
    sm[t] += x;
    __syncthreads();
  }
  int run = bsum[b] + sm[t] - s;   // exclusive prefix
  #pragma unroll
  for (int k = 0; k < 4; ++k){
    if (base + k < N){ row_ptr[base + k] = run; cursor[base + k] = run; run += v[k]; }
  }
}

__global__ __launch_bounds__(256) void edge_fill(
    const void* __restrict__ ei, const int* __restrict__ flags,
    int* __restrict__ cursor, int* __restrict__ bucket, int E, int N)
{
  int is64 = flags[1];
  int i = blockIdx.x * 256 + threadIdx.x, stride = gridDim.x * 256;
  for (int e = i; e < E; e += stride){
    int s, d; load_edge(ei, E, is64, e, s, d);
    if ((unsigned)s >= (unsigned)N || (unsigned)d >= (unsigned)N) continue;
    int slot = atomicAdd(cursor + d, 1);
    bucket[slot] = s;
  }
}

// ---------------- gather-reduce ----------------
// wave per node, lane = feature. max of bf16 values is exact in bf16.
__global__ __launch_bounds__(256) void gather_max64(
    const int* __restrict__ row_ptr, const int* __restrict__ bucket,
    const unsigned short* __restrict__ m, unsigned short* __restrict__ agg, int N)
{
  int node = (int)((blockIdx.x * 256u + threadIdx.x) >> 6);
  int f = threadIdx.x & 63;
  if (node >= N) return;
  int rs = row_ptr[node], re = row_ptr[node + 1];
  float acc = 0.f;
  int j = rs;
  for (; j + 1 < re; j += 2){
    int s0 = bucket[j], s1 = bucket[j + 1];
    float v0 = bf2f(m[(size_t)s0 * 64 + f]);
    float v1 = bf2f(m[(size_t)s1 * 64 + f]);
    acc = fmaxf(acc, fmaxf(v0, v1));
  }
  if (j < re) acc = fmaxf(acc, bf2f(m[(size_t)bucket[j] * 64 + f]));
  agg[(size_t)node * 64 + f] = f2bf(acc);
}

// 32 lanes per node (8 nodes / block of 256).
__global__ __launch_bounds__(256) void gather_sum32(
    const int* __restrict__ row_ptr, const int* __restrict__ bucket,
    const float* __restrict__ h2, float* __restrict__ ssum, int N)
{
  int node = blockIdx.x * 8 + (threadIdx.x >> 5);
  int f = threadIdx.x & 31;
  if (node >= N) return;
  int rs = row_ptr[node], re = row_ptr[node + 1];
  float acc = 0.f;
  int j = rs;
  for (; j + 1 < re; j += 2){
    int s0 = bucket[j], s1 = bucket[j + 1];
    acc += h2[(size_t)s0 * 32 + f];
    acc += h2[(size_t)s1 * 32 + f];
  }
  if (j < re) acc += h2[(size_t)bucket[j] * 32 + f];
  ssum[(size_t)node * 32 + f] = acc;
}

// ---------------- dense row transforms ----------------
// out[r] = act( A[r]@Wa + (B[r]*scale)@Wb + bias ). One row per thread.
// AMODE: 0=A bf16, 1=A f32, 2=runtime(flags[0]). BMODE: 0=none, 1=f32, 2=bf16.
// MEAN: scale = 1/max(deg,1), deg from row_ptr.
template<int K, int C, bool RELU, int BMODE, bool MEAN, bool OUTF32, int AMODE>
__global__ __launch_bounds__(256) void dual_mm(
    const void* __restrict__ Av, const void* __restrict__ Bv,
    const float* __restrict__ Wa, const float* __restrict__ Wb,
    const float* __restrict__ bias, const int* __restrict__ row_ptr,
    const int* __restrict__ flags, void* __restrict__ outv, int n)
{
  int r = blockIdx.x * 256 + threadIdx.x;
  if (r >= n) return;

  bool af32 = (AMODE == 1) || (AMODE == 2 && flags[0] == 0);
  float a[K];
  if (af32){
    const float4* ap = (const float4*)((const float*)Av + (size_t)r * K);
    #pragma unroll
    for (int k4 = 0; k4 < K / 4; ++k4){
      float4 v = ap[k4];
      a[4*k4+0] = v.x; a[4*k4+1] = v.y; a[4*k4+2] = v.z; a[4*k4+3] = v.w;
    }
  } else {
    const uint4* ap = (const uint4*)((const unsigned short*)Av + (size_t)r * K);
    #pragma unroll
    for (int k8 = 0; k8 < K / 8; ++k8){
      uint4 pk = ap[k8];
      a[k8*8+0] = __uint_as_float(pk.x << 16); a[k8*8+1] = __uint_as_float(pk.x & 0xffff0000u);
      a[k8*8+2] = __uint_as_float(pk.y << 16); a[k8*8+3] = __uint_as_float(pk.y & 0xffff0000u);
      a[k8*8+4] = __uint_as_float(pk.z << 16); a[k8*8+5] = __uint_as_float(pk.z & 0xffff0000u);
      a[k8*8+6] = __uint_as_float(pk.w << 16); a[k8*8+7] = __uint_as_float(pk.w & 0xffff0000u);
    }
  }
  float b[BMODE ? K : 1];
  if constexpr (BMODE == 1){
    float scale = 1.f;
    if constexpr (MEAN){
      int deg = row_ptr[r + 1] - row_ptr[r];
      scale = 1.f / fmaxf((float)deg, 1.f);
    }
    const float4* bp = (const float4*)((const float*)Bv + (size_t)r * K);
    #pragma unroll
    for (int k4 = 0; k4 < K / 4; ++k4){
      float4 v = bp[k4];
      b[4*k4+0] = v.x * scale; b[4*k4+1] = v.y * scale;
      b[4*k4+2] = v.z * scale; b[4*k4+3] = v.w * scale;
    }
  } else if constexpr (BMODE == 2){
    const uint4* bp = (const uint4*)((const unsigned short*)Bv + (size_t)r * K);
    #pragma unroll
    for (int k8 = 0; k8 < K / 8; ++k8){
      uint4 pk = bp[k8];
      b[k8*8+0] = __uint_as_float(pk.x << 16); b[k8*8+1] = __uint_as_float(pk.x & 0xffff0000u);
      b[k8*8+2] = __uint_as_float(pk.y << 16); b[k8*8+3] = __uint_as_float(pk.y & 0xffff0000u);
      b[k8*8+4] = __uint_as_float(pk.z << 16); b[k8*8+5] = __uint_as_float(pk.z & 0xffff0000u);
      b[k8*8+6] = __uint_as_float(pk.w << 16); b[k8*8+7] = __uint_as_float(pk.w & 0xffff0000u);
    }
  }
  #pragma unroll
  for (int c0 = 0; c0 < C; c0 += 8){
    float acc[8];
    #pragma unroll
    for (int j = 0; j < 8; ++j) acc[j] = bias[c0 + j];
    #pragma unroll
    for (int k = 0; k < K; ++k){
      float av = a[k];
      #pragma unroll
      for (int j = 0; j < 8; ++j) acc[j] = fmaf(av, Wa[k * C + c0 + j], acc[j]);
    }
    if constexpr (BMODE != 0){
      #pragma unroll
      for (int k = 0; k < K; ++k){
        float bv = b[k];
        #pragma unroll
        for (int j = 0; j < 8; ++j) acc[j] = fmaf(bv, Wb[k * C + c0 + j], acc[j]);
      }
    }
    #pragma unroll
    for (int j = 0; j < 8; ++j){ if constexpr (RELU) acc[j] = fmaxf(acc[j], 0.f); }

    if constexpr (OUTF32){
      float* orow = (float*)outv + (size_t)r * C + c0;
      float4 v0 = {acc[0], acc[1], acc[2], acc[3]};
      float4 v1 = {acc[4], acc[5], acc[6], acc[7]};
      *(float4*)(orow) = v0;
      *(float4*)(orow + 4) = v1;
    } else {
      unsigned short* orow = (unsigned short*)outv + (size_t)r * C + c0;
      uint4 pk;
      pk.x = (uint)f2bf(acc[0]) | ((uint)f2bf(acc[1]) << 16);
      pk.y = (uint)f2bf(acc[2]) | ((uint)f2bf(acc[3]) << 16);
      pk.z = (uint)f2bf(acc[4]) | ((uint)f2bf(acc[5]) << 16);
      pk.w = (uint)f2bf(acc[6]) | ((uint)f2bf(acc[7]) << 16);
      *(uint4*)(orow) = pk;
    }
  }
}

static inline char* align16(char* p){
  return (char*)(((uintptr_t)p + 15) & ~(uintptr_t)15);
}

extern "C" void kernel_launch(void* const* d_in, const int* in_sizes, int n_in,
                              void* d_out, int out_size, void* d_ws, size_t ws_size,
                              hipStream_t stream)
{
  const void* x = d_in[0];
  const void* ei = d_in[1];
  int N = in_sizes[0] / 64;   // 100000
  int E = in_sizes[1] / 2;    // 1600000

  char* ws = (char*)d_ws;
  float* wf = (float*)ws;      // 22784 floats; 128KB reserved incl. flags
  float* W1p = wf + 0;     float* b1p = wf + 4096;
  float* W1s = wf + 4160;  float* W1n = wf + 8256;  float* b1 = wf + 12352;
  float* W2p = wf + 12416; float* b2p = wf + 16512;
  float* W2s = wf + 16576; float* W2n = wf + 18624; float* b2 = wf + 20672;
  float* W3s = wf + 20704; float* W3n = wf + 21728; float* b3 = wf + 22752;
  int* flags = (int*)(ws + 131072 - 256);

  // big buffers (~46.3MB total; R2's 51.7MB fit)
  char* p = ws + 131072;
  int* deg     = (int*)p; p = align16(p + (size_t)N * 4);
  int* cursor  = (int*)p; p = align16(p + (size_t)N * 4);
  int* row_ptr = (int*)p; p = align16(p + (size_t)(N + 1) * 4);
  int* bsum    = (int*)p; p = align16(p + 4096);
  int* bucket  = (int*)p; p = align16(p + (size_t)E * 4);
  unsigned short* mbuf = (unsigned short*)p; p = align16(p + (size_t)N * 64 * 2);
  float* agg3 = (float*)mbuf;  // N*32 f32 == N*64 bf16 bytes; mbuf dead by then
  unsigned short* aggb = (unsigned short*)p; p = align16(p + (size_t)N * 64 * 2);
  unsigned short* h1   = (unsigned short*)p; p = align16(p + (size_t)N * 64 * 2);
  float* h2 = (float*)d_out;   // N*32 f32 == d_out; dead until final kernel

  hipLaunchKernelGGL(detect_kernel, dim3(1), dim3(64), 0, stream,
                     (const unsigned short*)x, (const int*)ei, flags);

  WConv wc;
  {
    const int widx[13] = {2,3,4,5,6,7,8,9,10,11,12,13,14};
    float* wdst[13] = {W1p,b1p,W1s,W1n,b1,W2p,b2p,W2s,W2n,b2,W3s,W3n,b3};
    for (int i = 0; i < 13; ++i){
      wc.src[i] = d_in[widx[i]]; wc.dst[i] = wdst[i]; wc.n[i] = in_sizes[widx[i]];
    }
  }
  hipLaunchKernelGGL(conv_w, dim3(13), dim3(256), 0, stream, wc, flags);

  // ---- CSR build (once; shared by all 3 layers) ----
  int nb = (N + 1023) / 1024;
  int ge = (E + 255) / 256;
  hipMemsetAsync(deg, 0, (size_t)N * 4, stream);
  edge_hist<<<ge, 256, 0, stream>>>(ei, flags, deg, E, N);
  scan_blocksums<<<nb, 256, 0, stream>>>(deg, bsum, N);
  scan_bsum<<<1, 256, 0, stream>>>(bsum, nb, row_ptr + N);
  scan_final<<<nb, 256, 0, stream>>>(deg, bsum, row_ptr, cursor, N);
  edge_fill<<<ge, 256, 0, stream>>>(ei, flags, cursor, bucket, E, N);

  int gmm = (N + 255) / 256;
  int ggm = (N + 3) / 4;      // gather_max64: 4 nodes (waves) per block
  int ggs = (N + 7) / 8;      // gather_sum32: 8 nodes per block

  // ---- layer 1 (pool 64->64, relu) ----
  dual_mm<64,64,true,0,false,false,2><<<gmm,256,0,stream>>>(
      x, nullptr, W1p, nullptr, b1p, nullptr, flags, mbuf, N);
  gather_max64<<<ggm,256,0,stream>>>(row_ptr, bucket, mbuf, aggb, N);
  dual_mm<64,64,true,2,false,false,2><<<gmm,256,0,stream>>>(
      x, aggb, W1s, W1n, b1, nullptr, flags, h1, N);

  // ---- layer 2 (pool 64->32, no act); h2 lives in d_out ----
  dual_mm<64,64,true,0,false,false,0><<<gmm,256,0,stream>>>(
      h1, nullptr, W2p, nullptr, b2p, nullptr, flags, mbuf, N);
  gather_max64<<<ggm,256,0,stream>>>(row_ptr, bucket, mbuf, aggb, N);
  dual_mm<64,32,false,2,false,true,0><<<gmm,256,0,stream>>>(
      h1, aggb, W2s, W2n, b2, nullptr, flags, h2, N);

  // ---- layer 3 (mean 32->32, f32 out, in-place on d_out) ----
  gather_sum32<<<ggs,256,0,stream>>>(row_ptr, bucket, h2, agg3, N);
  dual_mm<32,32,false,1,true,true,1><<<gmm,256,0,stream>>>(
      h2, agg3, W3s, W3n, b3, row_ptr, flags, d_out, N);
}

// Round 4
// 567.198 us; speedup vs baseline: 1.9716x; 1.5020x over previous
//
#include <hip/hip_runtime.h>
#include <hip/hip_bf16.h>

// GraphSAGE 3-layer: pool(64->64) -> pool(64->32) -> mean(32->32)
// R4: (1) two-phase LDS-staged CSR build (R3 edge_fill wrote 105MB for a 6.4MB
// bucket via scattered-4B write-through); (2) bf16 MFMA for all dense row
// transforms (R3 dual_mm was f32 vector-FMA bound).

typedef unsigned int uint;
typedef short short8 __attribute__((ext_vector_type(8)));
typedef float f32x4 __attribute__((ext_vector_type(4)));

__device__ __forceinline__ float bf2f(unsigned short h){
  return __uint_as_float(((uint)h) << 16);
}
__device__ __forceinline__ unsigned short f2bf(float f){
  uint u = __float_as_uint(f);
  u += 0x7fffu + ((u >> 16) & 1u);   // RNE
  return (unsigned short)(u >> 16);
}

// flags[0]=1 if float inputs bf16 else f32; flags[1]=1 if edge_index int64.
__global__ void detect_kernel(const unsigned short* x, const int* ei, int* flags){
  int lane = threadIdx.x;  // 64 threads
  int sane = 0;
  #pragma unroll
  for (int k = 0; k < 4; ++k){
    int e = (x[(lane * 4 + k) * 2] >> 7) & 0xff;
    sane += (e >= 118 && e <= 134);
  }
  #pragma unroll
  for (int off = 32; off; off >>= 1) sane += __shfl_down(sane, off, 64);
  unsigned long long b = __ballot(ei[1 + 2 * lane] != 0);
  if (lane == 0){ flags[0] = (sane >= 128); flags[1] = (b == 0ull); }
}

// ---------------- weight prep: bf16 + transpose to WT[C][K] ----------------
struct WConv {
  const void* src[13];
  int n[13], isbias[13], Cs[13], K[13], off[13];
};

__global__ void conv_w(WConv wc, unsigned short* wtbase, float* bbase,
                       const int* flags){
  int t = blockIdx.x, n = wc.n[t];
  int isbf = flags[0];
  if (wc.isbias[t]){
    float* d = bbase + wc.off[t];
    for (int i = threadIdx.x; i < n; i += blockDim.x)
      d[i] = isbf ? bf2f(((const unsigned short*)wc.src[t])[i])
                  : ((const float*)wc.src[t])[i];
  } else {
    unsigned short* d = wtbase + wc.off[t];
    int Cs = wc.Cs[t], K = wc.K[t], Cm = (1 << Cs) - 1;
    for (int i = threadIdx.x; i < n; i += blockDim.x){
      int k = i >> Cs, c = i & Cm;
      unsigned short v = isbf ? ((const unsigned short*)wc.src[t])[i]
                              : f2bf(((const float*)wc.src[t])[i]);
      d[c * K + k] = v;
    }
  }
}

__device__ __forceinline__ void load_edge(const void* ei, int E, int is64, int e,
                                          int& s, int& d){
  if (is64){
    const long long* p = (const long long*)ei;
    s = (int)p[e]; d = (int)p[E + e];
  } else {
    const int* p = (const int*)ei;
    s = p[e]; d = p[E + e];
  }
}

// ---------------- CSR build ----------------
__global__ __launch_bounds__(256) void edge_hist(
    const void* __restrict__ ei, const int* __restrict__ flags,
    int* __restrict__ deg, int E, int N)
{
  int is64 = flags[1];
  int i = blockIdx.x * 256 + threadIdx.x, stride = gridDim.x * 256;
  for (int e = i; e < E; e += stride){
    int s, d; load_edge(ei, E, is64, e, s, d);
    if ((unsigned)s >= (unsigned)N || (unsigned)d >= (unsigned)N) continue;
    atomicAdd(deg + d, 1);
  }
}

__global__ __launch_bounds__(256) void scan_blocksums(
    const int* __restrict__ deg, int* __restrict__ bsum, int N)
{
  __shared__ int sm[256];
  int b = blockIdx.x, t = threadIdx.x;
  int base = b * 1024 + t * 4, s = 0;
  #pragma unroll
  for (int k = 0; k < 4; ++k) if (base + k < N) s += deg[base + k];
  sm[t] = s; __syncthreads();
  for (int off = 128; off; off >>= 1){
    if (t < off) sm[t] += sm[t + off];
    __syncthreads();
  }
  if (t == 0) bsum[b] = sm[0];
}

__global__ void scan_bsum(int* bsum, int nb, int* rowptrN){
  __shared__ int sm[1024];
  int t = threadIdx.x;
  for (int i = t; i < nb; i += 256) sm[i] = bsum[i];
  __syncthreads();
  if (t == 0){
    int run = 0;
    for (int i = 0; i < nb; ++i){ int v = sm[i]; sm[i] = run; run += v; }
    *rowptrN = run;
  }
  __syncthreads();
  for (int i = t; i < nb; i += 256) bsum[i] = sm[i];
}

__global__ __launch_bounds__(256) void scan_final(
    const int* __restrict__ deg, const int* __restrict__ bsum,
    int* __restrict__ row_ptr, int* __restrict__ cursor, int N)
{
  __shared__ int sm[256];
  int b = blockIdx.x, t = threadIdx.x;
  int base = b * 1024 + t * 4;
  int v[4], s = 0;
  #pragma unroll
  for (int k = 0; k < 4; ++k){ v[k] = (base + k < N) ? deg[base + k] : 0; s += v[k]; }
  sm[t] = s; __syncthreads();
  for (int off = 1; off < 256; off <<= 1){
    int x = (t >= off) ? sm[t - off] : 0;
    __syncthreads();
    sm[t] += x;
    __syncthreads();
  }
  int run = bsum[b] + sm[t] - s;   // exclusive prefix
  #pragma unroll
  for (int k = 0; k < 4; ++k){
    if (base + k < N){ row_ptr[base + k] = run; cursor[base + k] = run; run += v[k]; }
  }
}

__global__ void ccur_init(const int* row_ptr, int* ccur, int NB, int S, int N){
  int b = threadIdx.x + blockIdx.x * 1024;
  if (b < NB){
    int node = b << S; if (node > N) node = N;
    ccur[b] = row_ptr[node];
  }
}

// phase1: multisplit edges into coarse buckets (dst>>S) as (src,dst) pairs.
// Per-block LDS hist + chunk reservation -> contiguous pair runs (~84B each).
#define CSR_CE 8192
__global__ __launch_bounds__(256) void csr_phase1(
    const void* __restrict__ ei, const int* __restrict__ flags,
    int* __restrict__ ccur, uint2* __restrict__ pairs,
    int E, int N, int NB, int S)
{
  __shared__ uint hist[1024];
  __shared__ uint gbase[1024];
  int is64 = flags[1];
  int t = threadIdx.x;
  int e0 = blockIdx.x * CSR_CE;
  for (int i = t; i < 1024; i += 256) hist[i] = 0;
  __syncthreads();
  #pragma unroll 4
  for (int it = 0; it < CSR_CE / 256; ++it){
    int e = e0 + it * 256 + t;
    if (e >= E) break;
    int s, d; load_edge(ei, E, is64, e, s, d);
    if ((unsigned)s >= (unsigned)N || (unsigned)d >= (unsigned)N) continue;
    atomicAdd(&hist[d >> S], 1u);
  }
  __syncthreads();
  for (int b = t; b < NB; b += 256){
    uint c = hist[b];
    if (c) gbase[b] = (uint)atomicAdd(&ccur[b], (int)c);
    hist[b] = 0;
  }
  __syncthreads();
  #pragma unroll 4
  for (int it = 0; it < CSR_CE / 256; ++it){
    int e = e0 + it * 256 + t;
    if (e >= E) break;
    int s, d; load_edge(ei, E, is64, e, s, d);
    if ((unsigned)s >= (unsigned)N || (unsigned)d >= (unsigned)N) continue;
    int b = d >> S;
    uint local = atomicAdd(&hist[b], 1u);
    uint slot = gbase[b] + local;
    pairs[slot] = make_uint2((uint)s, (uint)d);
  }
}

// phase2: one block per coarse bucket; exact per-node placement in LDS, then
// coalesced flush to bucket[]. Fallback to global atomics if region > cap.
#define P2_CAP 6144
__global__ __launch_bounds__(256) void csr_phase2(
    const int* __restrict__ row_ptr, const uint2* __restrict__ pairs,
    int* __restrict__ bucket, int* __restrict__ cursor, int N, int S)
{
  __shared__ int lbuf[P2_CAP];
  __shared__ int lcur[1024];
  int b = blockIdx.x, t = threadIdx.x;
  int n0 = b << S;
  int n1 = n0 + (1 << S); if (n1 > N) n1 = N;
  int nn = n1 - n0;
  int base = row_ptr[n0], end = row_ptr[n1], cnt = end - base;
  if (cnt <= 0) return;
  if (cnt <= P2_CAP && nn <= 1024){
    for (int i = t; i < nn; i += 256) lcur[i] = row_ptr[n0 + i] - base;
    __syncthreads();
    for (int j = base + t; j < end; j += 256){
      uint2 pr = pairs[j];
      int pos = atomicAdd(&lcur[(int)pr.y - n0], 1);
      lbuf[pos] = (int)pr.x;
    }
    __syncthreads();
    for (int i = t; i < cnt; i += 256) bucket[base + i] = lbuf[i];
  } else {
    for (int j = base + t; j < end; j += 256){
      uint2 pr = pairs[j];
      int slot = atomicAdd(&cursor[pr.y], 1);
      bucket[slot] = (int)pr.x;
    }
  }
}

// ---------------- gather-reduce ----------------
__global__ __launch_bounds__(256) void gather_max64(
    const int* __restrict__ row_ptr, const int* __restrict__ bucket,
    const unsigned short* __restrict__ m, unsigned short* __restrict__ agg, int N)
{
  int node = (int)((blockIdx.x * 256u + threadIdx.x) >> 6);
  int f = threadIdx.x & 63;
  if (node >= N) return;
  int rs = row_ptr[node], re = row_ptr[node + 1];
  float acc = 0.f;
  int j = rs;
  for (; j + 1 < re; j += 2){
    int s0 = bucket[j], s1 = bucket[j + 1];
    float v0 = bf2f(m[(size_t)s0 * 64 + f]);
    float v1 = bf2f(m[(size_t)s1 * 64 + f]);
    acc = fmaxf(acc, fmaxf(v0, v1));
  }
  if (j < re) acc = fmaxf(acc, bf2f(m[(size_t)bucket[j] * 64 + f]));
  agg[(size_t)node * 64 + f] = f2bf(acc);
}

// 32 lanes per node; h2 bf16 rows of 32 (64B). ssum out bf16.
__global__ __launch_bounds__(256) void gather_sum32(
    const int* __restrict__ row_ptr, const int* __restrict__ bucket,
    const unsigned short* __restrict__ h2, unsigned short* __restrict__ ssum, int N)
{
  int node = blockIdx.x * 8 + (threadIdx.x >> 5);
  int f = threadIdx.x & 31;
  if (node >= N) return;
  int rs = row_ptr[node], re = row_ptr[node + 1];
  float acc = 0.f;
  int j = rs;
  for (; j + 1 < re; j += 2){
    int s0 = bucket[j], s1 = bucket[j + 1];
    acc += bf2f(h2[(size_t)s0 * 32 + f]);
    acc += bf2f(h2[(size_t)s1 * 32 + f]);
  }
  if (j < re) acc += bf2f(h2[(size_t)bucket[j] * 32 + f]);
  ssum[(size_t)node * 32 + f] = f2bf(acc);
}

// ---------------- MFMA dense transforms ----------------
// D[N,C] = act( A[N,KA] @ WaT^T + aggpart + bias ). One 16x16 tile per wave.
// 16x16x32 bf16 fragments: A: lane holds A[m=lane&15][k=quad*8+j];
// B (weights): WT[C][K] so lane reads WT[n=lane&15][k=quad*8+j] contiguously;
// C/D: col=lane&15, row=quad*4+reg.
__device__ __forceinline__ short8 ld_fragA_bf16(const unsigned short* A, int row,
                                                int K, int koff){
  return *(const short8*)(A + (size_t)row * K + koff);
}
__device__ __forceinline__ short8 ld_fragA_f32(const float* A, int row,
                                               int K, int koff){
  const float* q = A + (size_t)row * K + koff;
  float4 f0 = *(const float4*)q;
  float4 f1 = *(const float4*)(q + 4);
  short8 r;
  r[0] = (short)f2bf(f0.x); r[1] = (short)f2bf(f0.y);
  r[2] = (short)f2bf(f0.z); r[3] = (short)f2bf(f0.w);
  r[4] = (short)f2bf(f1.x); r[5] = (short)f2bf(f1.y);
  r[6] = (short)f2bf(f1.z); r[7] = (short)f2bf(f1.w);
  return r;
}

// KA in {32,64}; KB in {0,32,64}; CT = C/16 in {2,4}; AMODE: 0=bf16, 2=runtime.
template<int KA, int KB, int CT, bool RELU, bool MEAN, bool OUTF32, int AMODE>
__global__ __launch_bounds__(256) void mfma_mm(
    const void* __restrict__ Av, const unsigned short* __restrict__ Bv,
    const unsigned short* __restrict__ WaT, const unsigned short* __restrict__ WbT,
    const float* __restrict__ bias, const int* __restrict__ row_ptr,
    const int* __restrict__ flags, void* __restrict__ outv, int N)
{
  constexpr int C = CT * 16;
  int wid = threadIdx.x >> 6, lane = threadIdx.x & 63;
  int g = blockIdx.x * 4 + wid;
  int rt, ct;
  if constexpr (CT == 4){ rt = g >> 2; ct = g & 3; }
  else                  { rt = g >> 1; ct = g & 1; }
  int RT = (N + 15) >> 4;
  if (rt >= RT) return;
  int m = lane & 15, quad = lane >> 4;
  int row = rt * 16 + m;
  int rowc = row < N ? row : N - 1;
  int colbase = ct * 16;
  int koq = quad * 8;

  bool af32 = (AMODE == 2) && (flags[0] == 0);
  f32x4 accS = {0.f, 0.f, 0.f, 0.f};
  f32x4 accA = {0.f, 0.f, 0.f, 0.f};

  #pragma unroll
  for (int k0 = 0; k0 < KA; k0 += 32){
    short8 af = af32 ? ld_fragA_f32((const float*)Av, rowc, KA, k0 + koq)
                     : ld_fragA_bf16((const unsigned short*)Av, rowc, KA, k0 + koq);
    short8 wf = *(const short8*)(WaT + (size_t)(colbase + m) * KA + k0 + koq);
    accS = __builtin_amdgcn_mfma_f32_16x16x32_bf16(af, wf, accS, 0, 0, 0);
  }
  if constexpr (KB > 0){
    #pragma unroll
    for (int k0 = 0; k0 < KB; k0 += 32){
      short8 bf = ld_fragA_bf16(Bv, rowc, KB, k0 + koq);
      short8 wf = *(const short8*)(WbT + (size_t)(colbase + m) * KB + k0 + koq);
      if constexpr (MEAN)
        accA = __builtin_amdgcn_mfma_f32_16x16x32_bf16(bf, wf, accA, 0, 0, 0);
      else
        accS = __builtin_amdgcn_mfma_f32_16x16x32_bf16(bf, wf, accS, 0, 0, 0);
    }
  }
  float bv = bias[colbase + m];
  #pragma unroll
  for (int r = 0; r < 4; ++r){
    int orow = rt * 16 + quad * 4 + r;
    if (orow >= N) continue;
    float v = accS[r] + bv;
    if constexpr (MEAN){
      int dg = row_ptr[orow + 1] - row_ptr[orow];
      v += accA[r] * (1.f / fmaxf((float)dg, 1.f));
    }
    if constexpr (RELU) v = fmaxf(v, 0.f);
    if constexpr (OUTF32)
      ((float*)outv)[(size_t)orow * C + colbase + m] = v;
    else
      ((unsigned short*)outv)[(size_t)orow * C + colbase + m] = f2bf(v);
  }
}

static inline char* align256(char* p){
  return (char*)(((uintptr_t)p + 255) & ~(uintptr_t)255);
}

extern "C" void kernel_launch(void* const* d_in, const int* in_sizes, int n_in,
                              void* d_out, int out_size, void* d_ws, size_t ws_size,
                              hipStream_t stream)
{
  const void* x = d_in[0];
  const void* ei = d_in[1];
  int N = in_sizes[0] / 64;   // 100000
  int E = in_sizes[1] / 2;    // 1600000

  char* ws = (char*)d_ws;
  unsigned short* wtbase = (unsigned short*)ws;     // 22528 ushorts (45KB)
  float* bbase = (float*)(ws + 65536);              // 256 floats
  int* flags = (int*)(ws + 131072 - 256);

  // coarse bucket shift
  int S = 7, NB = (N + 127) >> 7;
  while (NB > 1024){ S++; NB = (N + (1 << S) - 1) >> S; }

  // big buffers (~46MB): P aliases pairs->mbuf->h2; Q aliases aggb->ssum.
  char* p = ws + 131072;
  int* deg     = (int*)p; p = align256(p + (size_t)N * 4);
  int* row_ptr = (int*)p; p = align256(p + (size_t)(N + 1) * 4);
  int* cursor  = (int*)p; p = align256(p + (size_t)N * 4);
  int* ccur    = (int*)p; p = align256(p + 4096);
  int* bsum    = (int*)p; p = align256(p + 4096);
  int* bucket  = (int*)p; p = align256(p + (size_t)E * 4);
  char* P = p;  p = align256(p + (size_t)E * 8);          // >= N*64*2
  char* Q = p;  p = align256(p + (size_t)N * 64 * 2);
  char* R = p;  p = align256(p + (size_t)N * 64 * 2);
  uint2* pairs = (uint2*)P;
  unsigned short* mbuf = (unsigned short*)P;
  unsigned short* h2   = (unsigned short*)P;   // N*32 bf16, after mbuf dead
  unsigned short* aggb = (unsigned short*)Q;
  unsigned short* ssum = (unsigned short*)Q;   // after aggb dead
  unsigned short* h1   = (unsigned short*)R;

  hipLaunchKernelGGL(detect_kernel, dim3(1), dim3(64), 0, stream,
                     (const unsigned short*)x, (const int*)ei, flags);

  // weight prep: transpose to WT[C][K] bf16 + f32 biases
  WConv wc;
  {
    //                 W1p b1p W1s W1n b1  W2p b2p W2s  W2n  b2  W3s  W3n  b3
    const int widx[13] = {2, 3, 4, 5, 6, 7, 8, 9, 10, 11, 12, 13, 14};
    const int isb[13]  = {0, 1, 0, 0, 1, 0, 1, 0, 0, 1, 0, 0, 1};
    const int Cs[13]   = {6, 0, 6, 6, 0, 6, 0, 5, 5, 0, 5, 5, 0};
    const int Kk[13]   = {64, 0, 64, 64, 0, 64, 0, 64, 64, 0, 32, 32, 0};
    const int off[13]  = {0, 0, 4096, 8192, 64, 12288, 128, 16384, 18432, 192,
                          20480, 21504, 224};
    for (int i = 0; i < 13; ++i){
      wc.src[i] = d_in[widx[i]]; wc.n[i] = in_sizes[widx[i]];
      wc.isbias[i] = isb[i]; wc.Cs[i] = Cs[i]; wc.K[i] = Kk[i]; wc.off[i] = off[i];
    }
  }
  hipLaunchKernelGGL(conv_w, dim3(13), dim3(256), 0, stream, wc, wtbase, bbase, flags);
  unsigned short* W1pT = wtbase + 0;     unsigned short* W1sT = wtbase + 4096;
  unsigned short* W1nT = wtbase + 8192;  unsigned short* W2pT = wtbase + 12288;
  unsigned short* W2sT = wtbase + 16384; unsigned short* W2nT = wtbase + 18432;
  unsigned short* W3sT = wtbase + 20480; unsigned short* W3nT = wtbase + 21504;
  float* b1p = bbase + 0;  float* b1 = bbase + 64; float* b2p = bbase + 128;
  float* b2 = bbase + 192; float* b3 = bbase + 224;

  // ---- CSR build ----
  int nb = (N + 1023) / 1024;
  hipMemsetAsync(deg, 0, (size_t)N * 4, stream);
  edge_hist<<<(E + 255) / 256, 256, 0, stream>>>(ei, flags, deg, E, N);
  scan_blocksums<<<nb, 256, 0, stream>>>(deg, bsum, N);
  scan_bsum<<<1, 256, 0, stream>>>(bsum, nb, row_ptr + N);
  scan_final<<<nb, 256, 0, stream>>>(deg, bsum, row_ptr, cursor, N);
  ccur_init<<<(NB + 1023) / 1024, 1024, 0, stream>>>(row_ptr, ccur, NB, S, N);
  csr_phase1<<<(E + CSR_CE - 1) / CSR_CE, 256, 0, stream>>>(
      ei, flags, ccur, pairs, E, N, NB, S);
  csr_phase2<<<NB, 256, 0, stream>>>(row_ptr, pairs, bucket, cursor, N, S);

  int RT = (N + 15) / 16;
  int gc4 = (RT * 4 + 3) / 4;   // CT=4 kernels
  int gc2 = (RT * 2 + 3) / 4;   // CT=2 kernels
  int ggm = (N + 3) / 4;
  int ggs = (N + 7) / 8;

  // ---- layer 1 (pool 64->64, relu) ----
  mfma_mm<64,0,4,true,false,false,2><<<gc4,256,0,stream>>>(
      x, nullptr, W1pT, nullptr, b1p, nullptr, flags, mbuf, N);
  gather_max64<<<ggm,256,0,stream>>>(row_ptr, bucket, mbuf, aggb, N);
  mfma_mm<64,64,4,true,false,false,2><<<gc4,256,0,stream>>>(
      x, aggb, W1sT, W1nT, b1, nullptr, flags, h1, N);

  // ---- layer 2 (pool 64->32) ----
  mfma_mm<64,0,4,true,false,false,0><<<gc4,256,0,stream>>>(
      h1, nullptr, W2pT, nullptr, b2p, nullptr, flags, mbuf, N);
  gather_max64<<<ggm,256,0,stream>>>(row_ptr, bucket, mbuf, aggb, N);
  mfma_mm<64,64,2,false,false,false,0><<<gc2,256,0,stream>>>(
      h1, aggb, W2sT, W2nT, b2, nullptr, flags, h2, N);

  // ---- layer 3 (mean 32->32, f32 out) ----
  gather_sum32<<<ggs,256,0,stream>>>(row_ptr, bucket, h2, ssum, N);
  mfma_mm<32,32,2,false,true,true,0><<<gc2,256,0,stream>>>(
      h2, ssum, W3sT, W3nT, b3, row_ptr, flags, d_out, N);
}

// Round 5
// 377.347 us; speedup vs baseline: 2.9635x; 1.5031x over previous
//
#include <hip/hip_runtime.h>
#include <hip/hip_bf16.h>

// GraphSAGE 3-layer: pool(64->64) -> pool(64->32) -> mean(32->32)
// R5: (1) vectorized gather (4 rows per wave-load via lane remap + shfl-
// broadcast bucket indices; R4 gather was latency-bound at 100us/dispatch,
// VALUBusy 28%); (2) CSR build: coarse-hist phase0 + per-bucket LDS row_ptr
// derivation in phase2 (drops edge_hist's 1.6M global atomics + 3 scans).

typedef unsigned int uint;
typedef short short8 __attribute__((ext_vector_type(8)));
typedef float f32x4 __attribute__((ext_vector_type(4)));

__device__ __forceinline__ float bf2f(unsigned short h){
  return __uint_as_float(((uint)h) << 16);
}
__device__ __forceinline__ unsigned short f2bf(float f){
  uint u = __float_as_uint(f);
  u += 0x7fffu + ((u >> 16) & 1u);   // RNE
  return (unsigned short)(u >> 16);
}
__device__ __forceinline__ float lo16(uint u){ return __uint_as_float(u << 16); }
__device__ __forceinline__ float hi16(uint u){ return __uint_as_float(u & 0xffff0000u); }

// flags[0]=1 if float inputs bf16 else f32; flags[1]=1 if edge_index int64.
__global__ void detect_kernel(const unsigned short* x, const int* ei, int* flags){
  int lane = threadIdx.x;  // 64 threads
  int sane = 0;
  #pragma unroll
  for (int k = 0; k < 4; ++k){
    int e = (x[(lane * 4 + k) * 2] >> 7) & 0xff;
    sane += (e >= 118 && e <= 134);
  }
  #pragma unroll
  for (int off = 32; off; off >>= 1) sane += __shfl_down(sane, off, 64);
  unsigned long long b = __ballot(ei[1 + 2 * lane] != 0);
  if (lane == 0){ flags[0] = (sane >= 128); flags[1] = (b == 0ull); }
}

// ---------------- weight prep: bf16 + transpose to WT[C][K] ----------------
struct WConv {
  const void* src[13];
  int n[13], isbias[13], Cs[13], K[13], off[13];
};

__global__ void conv_w(WConv wc, unsigned short* wtbase, float* bbase,
                       const int* flags){
  int t = blockIdx.x, n = wc.n[t];
  int isbf = flags[0];
  if (wc.isbias[t]){
    float* d = bbase + wc.off[t];
    for (int i = threadIdx.x; i < n; i += blockDim.x)
      d[i] = isbf ? bf2f(((const unsigned short*)wc.src[t])[i])
                  : ((const float*)wc.src[t])[i];
  } else {
    unsigned short* d = wtbase + wc.off[t];
    int Cs = wc.Cs[t], K = wc.K[t], Cm = (1 << Cs) - 1;
    for (int i = threadIdx.x; i < n; i += blockDim.x){
      int k = i >> Cs, c = i & Cm;
      unsigned short v = isbf ? ((const unsigned short*)wc.src[t])[i]
                              : f2bf(((const float*)wc.src[t])[i]);
      d[c * K + k] = v;
    }
  }
}

__device__ __forceinline__ void load_edge(const void* ei, int E, int is64, int e,
                                          int& s, int& d){
  if (is64){
    const long long* p = (const long long*)ei;
    s = (int)p[e]; d = (int)p[E + e];
  } else {
    const int* p = (const int*)ei;
    s = p[e]; d = p[E + e];
  }
}

// ---------------- CSR build ----------------
#define CSR_CE 8192

// phase0: coarse histogram (dst>>S) via LDS, flushed once per block.
__global__ __launch_bounds__(256) void csr_phase0(
    const void* __restrict__ ei, const int* __restrict__ flags,
    uint* __restrict__ chist, int E, int N, int NB, int S)
{
  __shared__ uint h[1024];
  int is64 = flags[1], t = threadIdx.x;
  int e0 = blockIdx.x * CSR_CE;
  for (int i = t; i < 1024; i += 256) h[i] = 0;
  __syncthreads();
  #pragma unroll 4
  for (int it = 0; it < CSR_CE / 256; ++it){
    int e = e0 + it * 256 + t;
    if (e >= E) break;
    int s, d; load_edge(ei, E, is64, e, s, d);
    if ((unsigned)s >= (unsigned)N || (unsigned)d >= (unsigned)N) continue;
    atomicAdd(&h[d >> S], 1u);
  }
  __syncthreads();
  for (int i = t; i < NB; i += 256){ uint c = h[i]; if (c) atomicAdd(chist + i, c); }
}

// scan0: exclusive scan of coarse counts -> cbase[0..NB], ccur copy, row_ptr[N].
__global__ void csr_scan0(const uint* __restrict__ chist, int* __restrict__ cbase,
                          int* __restrict__ ccur, int* __restrict__ rowptrN, int NB)
{
  __shared__ int sm[256];
  int t = threadIdx.x;
  int g = (NB + 255) / 256;          // <= 4
  int vb = t * g, v[4], s = 0;
  for (int k = 0; k < g; ++k){
    int i = vb + k; int x = (i < NB) ? (int)chist[i] : 0; v[k] = x; s += x;
  }
  sm[t] = s; __syncthreads();
  for (int off = 1; off < 256; off <<= 1){
    int x = (t >= off) ? sm[t - off] : 0;
    __syncthreads(); sm[t] += x; __syncthreads();
  }
  int run = sm[t] - s;
  for (int k = 0; k < g; ++k){
    int i = vb + k;
    if (i < NB){ cbase[i] = run; ccur[i] = run; run += v[k]; }
  }
  if (t == 255){ cbase[NB] = run; *rowptrN = run; }
}

// phase1: multisplit edges into coarse buckets as (src,dst) pairs; per-block
// LDS hist + chunk reservation -> contiguous pair runs.
__global__ __launch_bounds__(256) void csr_phase1(
    const void* __restrict__ ei, const int* __restrict__ flags,
    int* __restrict__ ccur, uint2* __restrict__ pairs,
    int E, int N, int NB, int S)
{
  __shared__ uint hist[1024];
  __shared__ uint gbase[1024];
  int is64 = flags[1];
  int t = threadIdx.x;
  int e0 = blockIdx.x * CSR_CE;
  for (int i = t; i < 1024; i += 256) hist[i] = 0;
  __syncthreads();
  #pragma unroll 4
  for (int it = 0; it < CSR_CE / 256; ++it){
    int e = e0 + it * 256 + t;
    if (e >= E) break;
    int s, d; load_edge(ei, E, is64, e, s, d);
    if ((unsigned)s >= (unsigned)N || (unsigned)d >= (unsigned)N) continue;
    atomicAdd(&hist[d >> S], 1u);
  }
  __syncthreads();
  for (int b = t; b < NB; b += 256){
    uint c = hist[b];
    if (c) gbase[b] = (uint)atomicAdd(&ccur[b], (int)c);
    hist[b] = 0;
  }
  __syncthreads();
  #pragma unroll 4
  for (int it = 0; it < CSR_CE / 256; ++it){
    int e = e0 + it * 256 + t;
    if (e >= E) break;
    int s, d; load_edge(ei, E, is64, e, s, d);
    if ((unsigned)s >= (unsigned)N || (unsigned)d >= (unsigned)N) continue;
    int b = d >> S;
    uint local = atomicAdd(&hist[b], 1u);
    pairs[gbase[b] + local] = make_uint2((uint)s, (uint)d);
  }
}

// phase2: one block per coarse bucket. Per-node hist + scan in LDS -> writes
// row_ptr slice, then exact placement (LDS-staged flush when it fits).
#define P2_CAP 6144
__global__ __launch_bounds__(256) void csr_phase2(
    const int* __restrict__ cbase, const uint2* __restrict__ pairs,
    int* __restrict__ bucket, int* __restrict__ row_ptr, int N, int S)
{
  __shared__ int lbuf[P2_CAP];
  __shared__ int cur[1024];
  __shared__ int sm[256];
  int b = blockIdx.x, t = threadIdx.x;
  int n0 = b << S;
  int n1 = n0 + (1 << S); if (n1 > N) n1 = N;
  int nn = n1 - n0;
  int base = cbase[b], end = cbase[b + 1], cnt = end - base;

  for (int i = t; i < nn; i += 256) cur[i] = 0;
  __syncthreads();
  for (int j = base + t; j < end; j += 256)
    atomicAdd(&cur[(int)pairs[j].y - n0], 1);
  __syncthreads();
  // exclusive scan cur[0..nn) (nn <= 1024)
  int g = (nn + 255) / 256, vb = t * g, v[4], s = 0;
  for (int k = 0; k < g; ++k){
    int i = vb + k; int x = (i < nn) ? cur[i] : 0; v[k] = x; s += x;
  }
  sm[t] = s; __syncthreads();
  for (int off = 1; off < 256; off <<= 1){
    int x = (t >= off) ? sm[t - off] : 0;
    __syncthreads(); sm[t] += x; __syncthreads();
  }
  int run = sm[t] - s;
  for (int k = 0; k < g; ++k){
    int i = vb + k;
    if (i < nn){ row_ptr[n0 + i] = base + run; cur[i] = run; run += v[k]; }
  }
  __syncthreads();
  if (cnt <= 0) return;
  if (cnt <= P2_CAP){
    for (int j = base + t; j < end; j += 256){
      uint2 pr = pairs[j];
      int pos = atomicAdd(&cur[(int)pr.y - n0], 1);
      lbuf[pos] = (int)pr.x;
    }
    __syncthreads();
    for (int i = t; i < cnt; i += 256) bucket[base + i] = lbuf[i];
  } else {
    for (int j = base + t; j < end; j += 256){
      uint2 pr = pairs[j];
      int pos = atomicAdd(&cur[(int)pr.y - n0], 1);
      bucket[base + pos] = (int)pr.x;
    }
  }
}

// ---------------- gather-reduce (vectorized) ----------------
// wave per node. fg=lane&15 handles features [4fg..4fg+3] (uint2 = 8B);
// rowsel=lane>>4 picks edge j+rowsel -> one load fetches 4 full 128B rows.
__global__ __launch_bounds__(256) void gather_max64(
    const int* __restrict__ row_ptr, const int* __restrict__ bucket,
    const unsigned short* __restrict__ m, unsigned short* __restrict__ agg, int N)
{
  int node = (int)((blockIdx.x * 256u + threadIdx.x) >> 6);
  int lane = threadIdx.x & 63;
  if (node >= N) return;
  int rs = row_ptr[node], cnt = row_ptr[node + 1] - rs;
  int fg4 = (lane & 15) * 4, rowsel = lane >> 4;
  float a0 = 0.f, a1 = 0.f, a2 = 0.f, a3 = 0.f;
  for (int c0 = 0; c0 < cnt; c0 += 64){
    int chunk = min(cnt - c0, 64);
    int bval = (lane < chunk) ? bucket[rs + c0 + lane] : 0;
    int j = 0;
    for (; j + 8 <= chunk; j += 8){
      int s0 = __shfl(bval, j + rowsel, 64);
      int s1 = __shfl(bval, j + 4 + rowsel, 64);
      uint2 v0 = *(const uint2*)(m + (size_t)s0 * 64 + fg4);
      uint2 v1 = *(const uint2*)(m + (size_t)s1 * 64 + fg4);
      a0 = fmaxf(a0, fmaxf(lo16(v0.x), lo16(v1.x)));
      a1 = fmaxf(a1, fmaxf(hi16(v0.x), hi16(v1.x)));
      a2 = fmaxf(a2, fmaxf(lo16(v0.y), lo16(v1.y)));
      a3 = fmaxf(a3, fmaxf(hi16(v0.y), hi16(v1.y)));
    }
    for (; j < chunk; j += 4){
      int jj = j + rowsel;
      int s = __shfl(bval, jj & 63, 64);
      if (jj < chunk){
        uint2 v = *(const uint2*)(m + (size_t)s * 64 + fg4);
        a0 = fmaxf(a0, lo16(v.x)); a1 = fmaxf(a1, hi16(v.x));
        a2 = fmaxf(a2, lo16(v.y)); a3 = fmaxf(a3, hi16(v.y));
      }
    }
  }
  #pragma unroll
  for (int off = 16; off <= 32; off <<= 1){
    a0 = fmaxf(a0, __shfl_xor(a0, off, 64));
    a1 = fmaxf(a1, __shfl_xor(a1, off, 64));
    a2 = fmaxf(a2, __shfl_xor(a2, off, 64));
    a3 = fmaxf(a3, __shfl_xor(a3, off, 64));
  }
  if (lane < 16){
    uint2 pk;
    pk.x = (uint)f2bf(a0) | ((uint)f2bf(a1) << 16);
    pk.y = (uint)f2bf(a2) | ((uint)f2bf(a3) << 16);
    *(uint2*)(agg + (size_t)node * 64 + fg4) = pk;
  }
}

// wave per node; rows of 32 bf16 (64B). fg=lane&7, rowsel=lane>>3 -> 8 rows/load.
__global__ __launch_bounds__(256) void gather_sum32(
    const int* __restrict__ row_ptr, const int* __restrict__ bucket,
    const unsigned short* __restrict__ h2, unsigned short* __restrict__ ssum, int N)
{
  int node = (int)((blockIdx.x * 256u + threadIdx.x) >> 6);
  int lane = threadIdx.x & 63;
  if (node >= N) return;
  int rs = row_ptr[node], cnt = row_ptr[node + 1] - rs;
  int fg4 = (lane & 7) * 4, rowsel = lane >> 3;
  float a0 = 0.f, a1 = 0.f, a2 = 0.f, a3 = 0.f;
  for (int c0 = 0; c0 < cnt; c0 += 64){
    int chunk = min(cnt - c0, 64);
    int bval = (lane < chunk) ? bucket[rs + c0 + lane] : 0;
    int j = 0;
    for (; j + 16 <= chunk; j += 16){
      int s0 = __shfl(bval, j + rowsel, 64);
      int s1 = __shfl(bval, j + 8 + rowsel, 64);
      uint2 v0 = *(const uint2*)(h2 + (size_t)s0 * 32 + fg4);
      uint2 v1 = *(const uint2*)(h2 + (size_t)s1 * 32 + fg4);
      a0 += lo16(v0.x) + lo16(v1.x); a1 += hi16(v0.x) + hi16(v1.x);
      a2 += lo16(v0.y) + lo16(v1.y); a3 += hi16(v0.y) + hi16(v1.y);
    }
    for (; j < chunk; j += 8){
      int jj = j + rowsel;
      int s = __shfl(bval, jj & 63, 64);
      if (jj < chunk){
        uint2 v = *(const uint2*)(h2 + (size_t)s * 32 + fg4);
        a0 += lo16(v.x); a1 += hi16(v.x); a2 += lo16(v.y); a3 += hi16(v.y);
      }
    }
  }
  #pragma unroll
  for (int off = 8; off <= 32; off <<= 1){
    a0 += __shfl_xor(a0, off, 64);
    a1 += __shfl_xor(a1, off, 64);
    a2 += __shfl_xor(a2, off, 64);
    a3 += __shfl_xor(a3, off, 64);
  }
  if (lane < 8){
    uint2 pk;
    pk.x = (uint)f2bf(a0) | ((uint)f2bf(a1) << 16);
    pk.y = (uint)f2bf(a2) | ((uint)f2bf(a3) << 16);
    *(uint2*)(ssum + (size_t)node * 32 + fg4) = pk;
  }
}

// ---------------- MFMA dense transforms ----------------
__device__ __forceinline__ short8 ld_fragA_bf16(const unsigned short* A, int row,
                                                int K, int koff){
  return *(const short8*)(A + (size_t)row * K + koff);
}
__device__ __forceinline__ short8 ld_fragA_f32(const float* A, int row,
                                               int K, int koff){
  const float* q = A + (size_t)row * K + koff;
  float4 f0 = *(const float4*)q;
  float4 f1 = *(const float4*)(q + 4);
  short8 r;
  r[0] = (short)f2bf(f0.x); r[1] = (short)f2bf(f0.y);
  r[2] = (short)f2bf(f0.z); r[3] = (short)f2bf(f0.w);
  r[4] = (short)f2bf(f1.x); r[5] = (short)f2bf(f1.y);
  r[6] = (short)f2bf(f1.z); r[7] = (short)f2bf(f1.w);
  return r;
}

// KA in {32,64}; KB in {0,32,64}; CT = C/16 in {2,4}; AMODE: 0=bf16, 2=runtime.
template<int KA, int KB, int CT, bool RELU, bool MEAN, bool OUTF32, int AMODE>
__global__ __launch_bounds__(256) void mfma_mm(
    const void* __restrict__ Av, const unsigned short* __restrict__ Bv,
    const unsigned short* __restrict__ WaT, const unsigned short* __restrict__ WbT,
    const float* __restrict__ bias, const int* __restrict__ row_ptr,
    const int* __restrict__ flags, void* __restrict__ outv, int N)
{
  constexpr int C = CT * 16;
  int wid = threadIdx.x >> 6, lane = threadIdx.x & 63;
  int g = blockIdx.x * 4 + wid;
  int rt, ct;
  if constexpr (CT == 4){ rt = g >> 2; ct = g & 3; }
  else                  { rt = g >> 1; ct = g & 1; }
  int RT = (N + 15) >> 4;
  if (rt >= RT) return;
  int m = lane & 15, quad = lane >> 4;
  int row = rt * 16 + m;
  int rowc = row < N ? row : N - 1;
  int colbase = ct * 16;
  int koq = quad * 8;

  bool af32 = (AMODE == 2) && (flags[0] == 0);
  f32x4 accS = {0.f, 0.f, 0.f, 0.f};
  f32x4 accA = {0.f, 0.f, 0.f, 0.f};

  #pragma unroll
  for (int k0 = 0; k0 < KA; k0 += 32){
    short8 af = af32 ? ld_fragA_f32((const float*)Av, rowc, KA, k0 + koq)
                     : ld_fragA_bf16((const unsigned short*)Av, rowc, KA, k0 + koq);
    short8 wf = *(const short8*)(WaT + (size_t)(colbase + m) * KA + k0 + koq);
    accS = __builtin_amdgcn_mfma_f32_16x16x32_bf16(af, wf, accS, 0, 0, 0);
  }
  if constexpr (KB > 0){
    #pragma unroll
    for (int k0 = 0; k0 < KB; k0 += 32){
      short8 bf = ld_fragA_bf16(Bv, rowc, KB, k0 + koq);
      short8 wf = *(const short8*)(WbT + (size_t)(colbase + m) * KB + k0 + koq);
      if constexpr (MEAN)
        accA = __builtin_amdgcn_mfma_f32_16x16x32_bf16(bf, wf, accA, 0, 0, 0);
      else
        accS = __builtin_amdgcn_mfma_f32_16x16x32_bf16(bf, wf, accS, 0, 0, 0);
    }
  }
  float bv = bias[colbase + m];
  #pragma unroll
  for (int r = 0; r < 4; ++r){
    int orow = rt * 16 + quad * 4 + r;
    if (orow >= N) continue;
    float v = accS[r] + bv;
    if constexpr (MEAN){
      int dg = row_ptr[orow + 1] - row_ptr[orow];
      v += accA[r] * (1.f / fmaxf((float)dg, 1.f));
    }
    if constexpr (RELU) v = fmaxf(v, 0.f);
    if constexpr (OUTF32)
      ((float*)outv)[(size_t)orow * C + colbase + m] = v;
    else
      ((unsigned short*)outv)[(size_t)orow * C + colbase + m] = f2bf(v);
  }
}

static inline char* align256(char* p){
  return (char*)(((uintptr_t)p + 255) & ~(uintptr_t)255);
}

extern "C" void kernel_launch(void* const* d_in, const int* in_sizes, int n_in,
                              void* d_out, int out_size, void* d_ws, size_t ws_size,
                              hipStream_t stream)
{
  const void* x = d_in[0];
  const void* ei = d_in[1];
  int N = in_sizes[0] / 64;   // 100000
  int E = in_sizes[1] / 2;    // 1600000

  char* ws = (char*)d_ws;
  unsigned short* wtbase = (unsigned short*)ws;     // 22528 ushorts (45KB)
  float* bbase = (float*)(ws + 65536);              // 256 floats
  int* flags = (int*)(ws + 131072 - 256);

  int S = 7, NB = (N + 127) >> 7;
  while (NB > 1024){ S++; NB = (N + (1 << S) - 1) >> S; }

  // big buffers: P aliases pairs->mbuf->h2; Q aliases aggb->ssum.
  char* p = ws + 131072;
  int* row_ptr = (int*)p; p = align256(p + (size_t)(N + 1) * 4);
  uint* chist  = (uint*)p; p = align256(p + 4352);
  int* cbase   = (int*)p; p = align256(p + 4352);
  int* ccur    = (int*)p; p = align256(p + 4352);
  int* bucket  = (int*)p; p = align256(p + (size_t)E * 4);
  char* P = p;  p = align256(p + (size_t)E * 8);          // >= N*64*2
  char* Q = p;  p = align256(p + (size_t)N * 64 * 2);
  char* R = p;  p = align256(p + (size_t)N * 64 * 2);
  uint2* pairs = (uint2*)P;
  unsigned short* mbuf = (unsigned short*)P;
  unsigned short* h2   = (unsigned short*)P;   // after mbuf dead
  unsigned short* aggb = (unsigned short*)Q;
  unsigned short* ssum = (unsigned short*)Q;   // after aggb dead
  unsigned short* h1   = (unsigned short*)R;

  hipLaunchKernelGGL(detect_kernel, dim3(1), dim3(64), 0, stream,
                     (const unsigned short*)x, (const int*)ei, flags);

  WConv wc;
  {
    const int widx[13] = {2, 3, 4, 5, 6, 7, 8, 9, 10, 11, 12, 13, 14};
    const int isb[13]  = {0, 1, 0, 0, 1, 0, 1, 0, 0, 1, 0, 0, 1};
    const int Cs[13]   = {6, 0, 6, 6, 0, 6, 0, 5, 5, 0, 5, 5, 0};
    const int Kk[13]   = {64, 0, 64, 64, 0, 64, 0, 64, 64, 0, 32, 32, 0};
    const int off[13]  = {0, 0, 4096, 8192, 64, 12288, 128, 16384, 18432, 192,
                          20480, 21504, 224};
    for (int i = 0; i < 13; ++i){
      wc.src[i] = d_in[widx[i]]; wc.n[i] = in_sizes[widx[i]];
      wc.isbias[i] = isb[i]; wc.Cs[i] = Cs[i]; wc.K[i] = Kk[i]; wc.off[i] = off[i];
    }
  }
  hipLaunchKernelGGL(conv_w, dim3(13), dim3(256), 0, stream, wc, wtbase, bbase, flags);
  unsigned short* W1pT = wtbase + 0;     unsigned short* W1sT = wtbase + 4096;
  unsigned short* W1nT = wtbase + 8192;  unsigned short* W2pT = wtbase + 12288;
  unsigned short* W2sT = wtbase + 16384; unsigned short* W2nT = wtbase + 18432;
  unsigned short* W3sT = wtbase + 20480; unsigned short* W3nT = wtbase + 21504;
  float* b1p = bbase + 0;  float* b1 = bbase + 64; float* b2p = bbase + 128;
  float* b2 = bbase + 192; float* b3 = bbase + 224;

  // ---- CSR build ----
  int nP = (E + CSR_CE - 1) / CSR_CE;
  hipMemsetAsync(chist, 0, 4096, stream);
  csr_phase0<<<nP, 256, 0, stream>>>(ei, flags, chist, E, N, NB, S);
  csr_scan0<<<1, 256, 0, stream>>>(chist, cbase, ccur, row_ptr + N, NB);
  csr_phase1<<<nP, 256, 0, stream>>>(ei, flags, ccur, pairs, E, N, NB, S);
  csr_phase2<<<NB, 256, 0, stream>>>(cbase, pairs, bucket, row_ptr, N, S);

  int RT = (N + 15) / 16;
  int gc4 = RT;                 // CT=4: RT*4 waves / 4 per block
  int gc2 = (RT * 2 + 3) / 4;   // CT=2
  int gg = (N + 3) / 4;         // gathers: 4 nodes (waves) per block

  // ---- layer 1 (pool 64->64, relu) ----
  mfma_mm<64,0,4,true,false,false,2><<<gc4,256,0,stream>>>(
      x, nullptr, W1pT, nullptr, b1p, nullptr, flags, mbuf, N);
  gather_max64<<<gg,256,0,stream>>>(row_ptr, bucket, mbuf, aggb, N);
  mfma_mm<64,64,4,true,false,false,2><<<gc4,256,0,stream>>>(
      x, aggb, W1sT, W1nT, b1, nullptr, flags, h1, N);

  // ---- layer 2 (pool 64->32) ----
  mfma_mm<64,0,4,true,false,false,0><<<gc4,256,0,stream>>>(
      h1, nullptr, W2pT, nullptr, b2p, nullptr, flags, mbuf, N);
  gather_max64<<<gg,256,0,stream>>>(row_ptr, bucket, mbuf, aggb, N);
  mfma_mm<64,64,2,false,false,false,0><<<gc2,256,0,stream>>>(
      h1, aggb, W2sT, W2nT, b2, nullptr, flags, h2, N);

  // ---- layer 3 (mean 32->32, f32 out) ----
  gather_sum32<<<gg,256,0,stream>>>(row_ptr, bucket, h2, ssum, N);
  mfma_mm<32,32,2,false,true,true,0><<<gc2,256,0,stream>>>(
      h2, ssum, W3sT, W3nT, b3, row_ptr, flags, d_out, N);
}